// Round 17
// baseline (142.158 us; speedup 1.0000x reference)
//
#include <hip/hip_runtime.h>
#include <hip/hip_bf16.h>

// Shapes (fixed): B=4, T=64, L=128, D=768, H=12, d=64
#define NB 4
#define NT 64
#define NL 128
#define ND 768
#define NH 12
#define HD 64

typedef __attribute__((ext_vector_type(8))) short short8;
typedef __attribute__((ext_vector_type(4))) float f32x4;
typedef __attribute__((ext_vector_type(4))) unsigned int u32x4;

typedef __attribute__((address_space(3))) unsigned int lds_u32;
typedef __attribute__((address_space(1))) const unsigned int glob_u32;

static __device__ __forceinline__ unsigned short f2b(float x) {
    __hip_bfloat16 h = __float2bfloat16(x);   // RNE
    return *reinterpret_cast<unsigned short*>(&h);
}
static __device__ __forceinline__ float b2f(unsigned short u) {
    unsigned int v = ((unsigned int)u) << 16;
    union { unsigned int i; float f; } c; c.i = v; return c.f;
}
// async global->LDS, 16B/lane; LDS dest = base + lane*16 (wave-uniform base)
static __device__ __forceinline__ void gl2lds16(const void* g, void* l) {
    __builtin_amdgcn_global_load_lds((glob_u32*)g, (lds_u32*)l, 16, 0, 0);
}
// branchless RNE fp32->bf16 for two elems, packed into one u32 (no NaN inputs)
static __device__ __forceinline__ unsigned rne2(unsigned lo, unsigned hi) {
    lo += 0x7FFFu + ((lo >> 16) & 1u);
    hi += 0x7FFFu + ((hi >> 16) & 1u);
    return __builtin_amdgcn_perm(hi, lo, 0x07060302u);  // [hi31:16 | lo31:16]
}

// ---------------------------------------------------------------------------
// Kernel 1 (prep_all): round-14 proven merged kernel.
//  blocks [0,96):      kvm — K/V proj (bf16 MFMA, self-converting staging) +
//                      speaker-bucket scan (LDS buckets) -> Mt
//  blocks [96,3168):   dense te fp32->bf16 convert (16B/lane, ILP-8, NT loads)
//  blocks [3168,3240): Wq fp32->bf16 convert
// ---------------------------------------------------------------------------
__global__ __launch_bounds__(256) void prep_all(
    const float* __restrict__ te, const float* __restrict__ Wq,
    const float* __restrict__ edu, const float* __restrict__ Wk,
    const float* __restrict__ Wv, const int* __restrict__ spk,
    unsigned short* __restrict__ te_b, unsigned short* __restrict__ wq_b,
    unsigned short* __restrict__ Mt)
{
    __shared__ __align__(16) unsigned char sm[113920];
    const int tid = threadIdx.x;
    const unsigned bid = blockIdx.x;

    if (bid >= 96u) {
        if (bid < 3168u) {
            const unsigned base = (bid - 96u) * 2048u + tid;
            u32x4 a[8];
            #pragma unroll
            for (int i = 0; i < 8; i++)
                a[i] = __builtin_nontemporal_load((const u32x4*)te + base + i * 256u);
            #pragma unroll
            for (int i = 0; i < 8; i++) {
                uint2 o;
                o.x = rne2(a[i].x, a[i].y);
                o.y = rne2(a[i].z, a[i].w);
                *(uint2*)(te_b + (size_t)(base + i * 256u) * 4u) = o;
            }
        } else {
            const unsigned base = (bid - 3168u) * 2048u + tid;
            u32x4 a[8];
            #pragma unroll
            for (int i = 0; i < 8; i++)
                a[i] = *((const u32x4*)Wq + base + i * 256u);
            #pragma unroll
            for (int i = 0; i < 8; i++) {
                uint2 o;
                o.x = rne2(a[i].x, a[i].y);
                o.y = rne2(a[i].z, a[i].w);
                *(uint2*)(wq_b + (size_t)(base + i * 256u) * 4u) = o;
            }
        }
        return;
    }

    // ---- kvm path: bid < 96 -> (h, b, eh) ----
    const int h  = bid % 12;
    const int b  = (bid / 12) & 3;
    const int eh = bid / 48;

    float (*bucket)[32][65]  = (float (*)[32][65])(sm);            // 66560 B
    float (*k_s)[68]         = (float (*)[68])(sm + 66560);        // 17408 B
    float (*v_s)[36]         = (float (*)[36])(sm + 83968);        //  9216 B
    unsigned short* edu_s    = (unsigned short*)(sm + 93184);
    unsigned short* wk_s     = edu_s + 4096;
    unsigned short* wv_s     = edu_s + 8192;
    int* spk_s               = (int*)(sm + 113664);

    const int lane = tid & 63, wvx = tid >> 6;
    const int lr = lane & 15, lg = lane >> 4;

    { float* p = &bucket[0][0][0];
      for (int i = tid; i < 8 * 32 * 65; i += 256) p[i] = 0.f; }
    if (tid < 64) spk_s[tid] = spk[b * NT + tid];

    const float* eduf = edu + (size_t)(b * 64) * ND;
    const float* wkf  = Wk  + (size_t)(h * 64) * ND;
    const float* wvf  = Wv  + (size_t)(h * 64 + eh * 32) * ND;

    f32x4 acc_k[4], acc_v[2];
    #pragma unroll
    for (int i = 0; i < 4; i++) acc_k[i] = (f32x4){0.f, 0.f, 0.f, 0.f};
    #pragma unroll
    for (int i = 0; i < 2; i++) acc_v[i] = (f32x4){0.f, 0.f, 0.f, 0.f};

    for (int k0 = 0; k0 < ND; k0 += 64) {
        __syncthreads();
        #pragma unroll
        for (int i = 0; i < 2; i++) {           // edu: 2 chunks/thread
            const int g = tid * 2 + i, row = g >> 3, ch = g & 7;
            const u32x4* p = (const u32x4*)(eduf + (size_t)row * ND + k0 + ch * 8);
            u32x4 x = p[0], y = p[1];
            u32x4 o = { rne2(x.x, x.y), rne2(x.z, x.w), rne2(y.x, y.y), rne2(y.z, y.w) };
            *(u32x4*)&edu_s[row * 64 + ((ch ^ (row & 7)) * 8)] = o;
        }
        #pragma unroll
        for (int i = 0; i < 2; i++) {           // Wk: 2 chunks/thread
            const int g = tid * 2 + i, row = g >> 3, ch = g & 7;
            const u32x4* p = (const u32x4*)(wkf + (size_t)row * ND + k0 + ch * 8);
            u32x4 x = p[0], y = p[1];
            u32x4 o = { rne2(x.x, x.y), rne2(x.z, x.w), rne2(y.x, y.y), rne2(y.z, y.w) };
            *(u32x4*)&wk_s[row * 64 + ((ch ^ (row & 7)) * 8)] = o;
        }
        {                                        // Wv: 1 chunk/thread
            const int g = tid, row = g >> 3, ch = g & 7;
            const u32x4* p = (const u32x4*)(wvf + (size_t)row * ND + k0 + ch * 8);
            u32x4 x = p[0], y = p[1];
            u32x4 o = { rne2(x.x, x.y), rne2(x.z, x.w), rne2(y.x, y.y), rne2(y.z, y.w) };
            *(u32x4*)&wv_s[row * 64 + ((ch ^ (row & 7)) * 8)] = o;
        }
        __syncthreads();
        #pragma unroll
        for (int k32 = 0; k32 < 2; k32++) {
            const int cx = (((k32 * 4 + lg) ^ (lr & 7)) * 8);
            short8 eb = *(const short8*)&edu_s[(wvx * 16 + lr) * 64 + cx];
            #pragma unroll
            for (int jb = 0; jb < 4; jb++) {
                short8 ak = *(const short8*)&wk_s[(jb * 16 + lr) * 64 + cx];
                acc_k[jb] = __builtin_amdgcn_mfma_f32_16x16x32_bf16(ak, eb, acc_k[jb], 0, 0, 0);
            }
            #pragma unroll
            for (int jb = 0; jb < 2; jb++) {
                short8 av = *(const short8*)&wv_s[(jb * 16 + lr) * 64 + cx];
                acc_v[jb] = __builtin_amdgcn_mfma_f32_16x16x32_bf16(av, eb, acc_v[jb], 0, 0, 0);
            }
        }
    }

    {
        const int t = wvx * 16 + lr;
        #pragma unroll
        for (int jb = 0; jb < 4; jb++) *(f32x4*)&k_s[t][jb * 16 + lg * 4] = acc_k[jb];
        #pragma unroll
        for (int jb = 0; jb < 2; jb++) *(f32x4*)&v_s[t][jb * 16 + lg * 4] = acc_v[jb];
    }
    __syncthreads();

    const int e = tid & 31, dg = tid >> 5;
    for (int t = 0; t < NT; t++) {
        const int s = spk_s[t];
        const float vv = v_s[t][e];
        unsigned short tmp[8];
        #pragma unroll
        for (int jj = 0; jj < 8; jj++) {
            float m = bucket[s][e][dg * 8 + jj] + k_s[t][dg * 8 + jj] * vv;
            bucket[s][e][dg * 8 + jj] = m;
            tmp[jj] = f2b(m);
        }
        unsigned short* mpp = Mt + (((size_t)(b * NT + t) * NH + h) * HD + eh * 32 + e) * HD + dg * 8;
        *(short8*)mpp = *(short8*)tmp;
    }
}

// ---------------------------------------------------------------------------
// Kernel 2: fused bf16 MFMA. NEW vs round 13: Wq A-fragments loaded straight
// from global into double-buffered REG sets (wq is 1.2 MB, L2-hot across 256
// same-hp blocks — same regime as Mt). LDS = te0/te1 only (34.8 KB incl q_s
// overlay) -> 3 blocks/CU (was 2). Counted vmcnt(12) covers te(4)+wq(8).
// ---------------------------------------------------------------------------
__global__ __launch_bounds__(256, 3) void fused_qm(
    const unsigned short* __restrict__ te_b,
    const unsigned short* __restrict__ wq_b,
    const unsigned short* __restrict__ Mt,
    float* __restrict__ out)
{
    const int orig = blockIdx.x;
    const int id   = (orig & 7) * 192 + (orig >> 3);   // bijective XCD swizzle
    const int hp   = id % 6;
    const int bt   = id / 6;

    __shared__ __align__(16) unsigned short smem[17408];   // 34816 B
    unsigned short* te0 = smem;              // [128][64] swizzled chunks
    unsigned short* te1 = smem + 8192;
    unsigned short* q_s = smem;              // phase 2: [128][136]

    const int tid  = threadIdx.x;
    const int lane = tid & 63;
    const int wvx  = tid >> 6;
    const int lr   = lane & 15;
    const int lg   = lane >> 4;
    const int wm   = wvx >> 1;
    const int wn   = wvx & 1;
    const int r8   = lane >> 3;
    const int l8   = lane & 7;
    const int sswz = (l8 ^ r8) * 8;          // pre-swizzled source chunk (ush)

    const unsigned short* teb = te_b + (size_t)bt * NL * ND;
    const unsigned short* wqb = wq_b + (size_t)hp * 128 * ND;

    f32x4 acc[4][4];
    #pragma unroll
    for (int i = 0; i < 4; i++)
        #pragma unroll
        for (int j = 0; j < 4; j++) acc[i][j] = (f32x4){0.f, 0.f, 0.f, 0.f};

    short8 wqrA[8], wqrB[8];   // A-frag reg sets: [tm*2 + k32]

    auto STAGE_TE = [&](unsigned short* tebuf, int k0) {
        #pragma unroll
        for (int j = 0; j < 4; j++) {
            const int rbase = wvx * 32 + j * 8;     // wave-uniform dest base
            gl2lds16(teb + (size_t)(rbase + r8) * ND + k0 + sswz, tebuf + rbase * 64);
        }
    };
    auto LOADWQ = [&](short8 (&dst)[8], int k0) {
        #pragma unroll
        for (int tm = 0; tm < 4; tm++)
            #pragma unroll
            for (int k32 = 0; k32 < 2; k32++)
                dst[tm * 2 + k32] = *(const short8*)&wqb[
                    (size_t)(wm * 64 + tm * 16 + lr) * ND + k0 + k32 * 32 + lg * 8];
    };
    auto COMPUTE = [&](const unsigned short* tes, const short8 (&wqr)[8]) {
        #pragma unroll
        for (int k32 = 0; k32 < 2; k32++) {
            const int cx = (((k32 * 4 + lg) ^ (lr & 7)) * 8);
            short8 bfv[4];
            #pragma unroll
            for (int tn = 0; tn < 4; tn++)
                bfv[tn] = *(const short8*)&tes[(wn * 64 + tn * 16 + lr) * 64 + cx];
            #pragma unroll
            for (int tm = 0; tm < 4; tm++)
                #pragma unroll
                for (int tn = 0; tn < 4; tn++)
                    acc[tm][tn] = __builtin_amdgcn_mfma_f32_16x16x32_bf16(
                        wqr[tm * 2 + k32], bfv[tn], acc[tm][tn], 0, 0, 0);
        }
    };

    // ---- prologue: tile 0 (wq regs A + te0) ----
    LOADWQ(wqrA, 0);
    STAGE_TE(te0, 0);

    // ---- K-loop: 12 tiles, unrolled x2 (static reg-set names, rule #20) ----
    #pragma unroll
    for (int kt = 0; kt < 12; kt += 2) {
        // even tile kt: prefetch kt+1 (wqB + te1); wait tile kt complete
        LOADWQ(wqrB, (kt + 1) * 64);
        STAGE_TE(te1, (kt + 1) * 64);
        asm volatile("s_waitcnt vmcnt(12)" ::: "memory");  // te(kt)+wq(kt) done
        __builtin_amdgcn_sched_barrier(0);
        __builtin_amdgcn_s_barrier();
        COMPUTE(te0, wqrA);
        asm volatile("s_waitcnt lgkmcnt(0)" ::: "memory"); // LDS reads retired
        __builtin_amdgcn_s_barrier();                      // te0 free for reuse
        // odd tile kt+1: prefetch kt+2 (wqA + te0); wait tile kt+1 complete
        if (kt + 2 < 12) {
            LOADWQ(wqrA, (kt + 2) * 64);
            STAGE_TE(te0, (kt + 2) * 64);
            asm volatile("s_waitcnt vmcnt(12)" ::: "memory");
        } else {
            asm volatile("s_waitcnt vmcnt(0)" ::: "memory");
        }
        __builtin_amdgcn_sched_barrier(0);
        __builtin_amdgcn_s_barrier();
        COMPUTE(te1, wqrB);
        asm volatile("s_waitcnt lgkmcnt(0)" ::: "memory");
        __builtin_amdgcn_s_barrier();                      // te1 free for reuse
    }

    // ---- q^T C-frags -> row-major bf16 q_s[l][d] (8B packed writes) ----
    #pragma unroll
    for (int tm = 0; tm < 4; tm++) {
        const int d0 = wm * 64 + tm * 16 + lg * 4;
        #pragma unroll
        for (int tn = 0; tn < 4; tn++) {
            const int ltok = wn * 64 + tn * 16 + lr;
            f32x4 a = acc[tm][tn];
            uint2 w2;
            w2.x = (unsigned)f2b(a.x) | ((unsigned)f2b(a.y) << 16);
            w2.y = (unsigned)f2b(a.z) | ((unsigned)f2b(a.w) << 16);
            *(uint2*)&q_s[ltok * 136 + d0] = w2;
        }
    }

    // ---- GEMM2 B-frags straight from global Mt (L2-hot); issue pre-barrier --
    const int h2 = wvx & 1;
    const int lh = wvx >> 1;
    const unsigned short* mp = Mt + ((size_t)(bt * NH) + hp * 2 + h2) * (HD * HD);
    short8 bfr[8];
    #pragma unroll
    for (int tn = 0; tn < 4; tn++)
        #pragma unroll
        for (int k32 = 0; k32 < 2; k32++)
            bfr[tn * 2 + k32] =
                *(const short8*)&mp[(tn * 16 + lr) * 64 + k32 * 32 + lg * 8];
    __syncthreads();            // q_s visible

    // ---- GEMM2: per-wave one (token-half, head), 64x64, K=64 ----
    f32x4 acc2[4][4];
    #pragma unroll
    for (int i = 0; i < 4; i++)
        #pragma unroll
        for (int j = 0; j < 4; j++) acc2[i][j] = (f32x4){0.f, 0.f, 0.f, 0.f};

    #pragma unroll
    for (int k32 = 0; k32 < 2; k32++) {
        const int ko = k32 * 32 + lg * 8;
        short8 af[4];
        #pragma unroll
        for (int tm = 0; tm < 4; tm++)
            af[tm] = *(const short8*)&q_s[(lh * 64 + tm * 16 + lr) * 136 + h2 * 64 + ko];
        #pragma unroll
        for (int tm = 0; tm < 4; tm++)
            #pragma unroll
            for (int tn = 0; tn < 4; tn++)
                acc2[tm][tn] = __builtin_amdgcn_mfma_f32_16x16x32_bf16(
                    af[tm], bfr[tn * 2 + k32], acc2[tm][tn], 0, 0, 0);
    }

    // ---- epilogue: out = bf16(te) + a (te_b L2-hot from staging) ----
    float* ob = out + (size_t)bt * NL * ND;
    #pragma unroll
    for (int tm = 0; tm < 4; tm++) {
        const int l0 = lh * 64 + tm * 16 + lg * 4;
        #pragma unroll
        for (int tn = 0; tn < 4; tn++) {
            const int cg = hp * 128 + h2 * 64 + tn * 16 + lr;
            f32x4 a = acc2[tm][tn];
            #pragma unroll
            for (int r = 0; r < 4; r++) {
                size_t gi = (size_t)(l0 + r) * ND + cg;
                ob[gi] = b2f(teb[gi]) + a[r];
            }
        }
    }
}

// ---------------------------------------------------------------------------
extern "C" void kernel_launch(void* const* d_in, const int* in_sizes, int n_in,
                              void* d_out, int out_size, void* d_ws, size_t ws_size,
                              hipStream_t stream)
{
    const int*   spk = (const int*)d_in[1];
    const float* te  = (const float*)d_in[2];
    const float* edu = (const float*)d_in[3];
    const float* Wk  = (const float*)d_in[4];
    const float* Wv  = (const float*)d_in[5];
    const float* Wq  = (const float*)d_in[6];
    float* out = (float*)d_out;

    // ws layout (ush units), ~76.7 MB total:
    unsigned short* bf    = (unsigned short*)d_ws;
    unsigned short* te_bb = bf;                          // 25165824
    unsigned short* wq_bb = bf + 25165824u;              //   589824
    unsigned short* Mtbuf = bf + 25755648u;              // 12582912

    prep_all<<<3240, 256, 0, stream>>>(te, Wq, edu, Wk, Wv, spk,
                                       te_bb, wq_bb, Mtbuf);
    fused_qm<<<6 * NT * NB, 256, 0, stream>>>(te_bb, wq_bb, Mtbuf, out);
}

// Round 18
// 104.080 us; speedup vs baseline: 1.3659x; 1.3659x over previous
//
#include <hip/hip_runtime.h>
#include <hip/hip_bf16.h>

// Shapes (fixed): B=4, T=64, L=128, D=768, H=12, d=64
#define NB 4
#define NT 64
#define NL 128
#define ND 768
#define NH 12
#define HD 64

typedef __attribute__((ext_vector_type(8))) short short8;
typedef __attribute__((ext_vector_type(4))) float f32x4;
typedef __attribute__((ext_vector_type(4))) unsigned int u32x4;

typedef __attribute__((address_space(3))) unsigned int lds_u32;
typedef __attribute__((address_space(1))) const unsigned int glob_u32;

static __device__ __forceinline__ unsigned short f2b(float x) {
    __hip_bfloat16 h = __float2bfloat16(x);   // RNE
    return *reinterpret_cast<unsigned short*>(&h);
}
static __device__ __forceinline__ float b2f(unsigned short u) {
    unsigned int v = ((unsigned int)u) << 16;
    union { unsigned int i; float f; } c; c.i = v; return c.f;
}
static __device__ __forceinline__ unsigned fbits(float f) {
    union { float f; unsigned u; } c; c.f = f; return c.u;
}
// async global->LDS, 16B/lane; LDS dest = base + lane*16 (wave-uniform base)
static __device__ __forceinline__ void gl2lds16(const void* g, void* l) {
    __builtin_amdgcn_global_load_lds((glob_u32*)g, (lds_u32*)l, 16, 0, 0);
}
// branchless RNE fp32->bf16 for two elems, packed into one u32 (no NaN inputs)
static __device__ __forceinline__ unsigned rne2(unsigned lo, unsigned hi) {
    lo += 0x7FFFu + ((lo >> 16) & 1u);
    hi += 0x7FFFu + ((hi >> 16) & 1u);
    return __builtin_amdgcn_perm(hi, lo, 0x07060302u);  // [hi31:16 | lo31:16]
}

// ---------------------------------------------------------------------------
// Kernel 1 (prep_all): round-15 structure (27 KB LDS, register-bucket scan)
// + __launch_bounds__(256, 1): frees the register allocator so the kvm scan's
// 32 bucket regs stay in VGPRs (round 15: compiler chose 52 VGPR -> spilled
// -> 67 us). Converts at ~4-5 blocks/CU (was 1/CU in round 14's 114 KB LDS).
//  blocks [0,96):      kvm — K/V proj (bf16 MFMA, self-converting staging) +
//                      speaker scan with REGISTER buckets (1 speaker/wave)
//  blocks [96,3168):   dense te fp32->bf16 convert (16B/lane, ILP-8, NT loads)
//  blocks [3168,3240): Wq fp32->bf16 convert
// ---------------------------------------------------------------------------
__global__ __launch_bounds__(256, 1) void prep_all(
    const float* __restrict__ te, const float* __restrict__ Wq,
    const float* __restrict__ edu, const float* __restrict__ Wk,
    const float* __restrict__ Wv, const int* __restrict__ spk,
    unsigned short* __restrict__ te_b, unsigned short* __restrict__ wq_b,
    unsigned short* __restrict__ Mt)
{
    // phase1: staging  edu_s 8192 | wk_s 8192 | wv_s 4096   (@0, 20480 B)
    // phase2: k_s f32[64][68] (@0, 17408 B) | v_s f32[64][36] (@17408, 9216 B)
    // spk_s @26624 (256 B). Total 26880 B.
    __shared__ __align__(16) unsigned char sm[26880];
    const int tid = threadIdx.x;
    const unsigned bid = blockIdx.x;

    if (bid >= 96u) {
        if (bid < 3168u) {
            // ---- te convert: 6291456 4-float chunks = 3072 * 2048 ----
            const unsigned base = (bid - 96u) * 2048u + tid;
            u32x4 a[8];
            #pragma unroll
            for (int i = 0; i < 8; i++)
                a[i] = __builtin_nontemporal_load((const u32x4*)te + base + i * 256u);
            #pragma unroll
            for (int i = 0; i < 8; i++) {
                uint2 o;
                o.x = rne2(a[i].x, a[i].y);
                o.y = rne2(a[i].z, a[i].w);
                *(uint2*)(te_b + (size_t)(base + i * 256u) * 4u) = o;
            }
        } else {
            // ---- Wq convert: 147456 chunks = 72 * 2048 ----
            const unsigned base = (bid - 3168u) * 2048u + tid;
            u32x4 a[8];
            #pragma unroll
            for (int i = 0; i < 8; i++)
                a[i] = *((const u32x4*)Wq + base + i * 256u);
            #pragma unroll
            for (int i = 0; i < 8; i++) {
                uint2 o;
                o.x = rne2(a[i].x, a[i].y);
                o.y = rne2(a[i].z, a[i].w);
                *(uint2*)(wq_b + (size_t)(base + i * 256u) * 4u) = o;
            }
        }
        return;
    }

    // ---- kvm path: bid < 96 -> (h, b, eh) ----
    const int h  = bid % 12;
    const int b  = (bid / 12) & 3;
    const int eh = bid / 48;

    unsigned short* edu_s = (unsigned short*)(sm);
    unsigned short* wk_s  = (unsigned short*)(sm + 8192);
    unsigned short* wv_s  = (unsigned short*)(sm + 16384);
    float (*k_s)[68]      = (float (*)[68])(sm);             // phase 2 overlay
    float (*v_s)[36]      = (float (*)[36])(sm + 17408);
    int* spk_s            = (int*)(sm + 26624);

    const int lane = tid & 63, wvx = tid >> 6;
    const int lr = lane & 15, lg = lane >> 4;

    if (tid < 64) spk_s[tid] = spk[b * NT + tid];

    const float* eduf = edu + (size_t)(b * 64) * ND;
    const float* wkf  = Wk  + (size_t)(h * 64) * ND;
    const float* wvf  = Wv  + (size_t)(h * 64 + eh * 32) * ND;

    f32x4 acc_k[4], acc_v[2];
    #pragma unroll
    for (int i = 0; i < 4; i++) acc_k[i] = (f32x4){0.f, 0.f, 0.f, 0.f};
    #pragma unroll
    for (int i = 0; i < 2; i++) acc_v[i] = (f32x4){0.f, 0.f, 0.f, 0.f};

    for (int k0 = 0; k0 < ND; k0 += 64) {
        __syncthreads();
        // self-convert staging: fp32 load -> rne2 -> swizzled bf16 ds_write
        #pragma unroll
        for (int i = 0; i < 2; i++) {           // edu: 2 chunks/thread
            const int g = tid * 2 + i, row = g >> 3, ch = g & 7;
            const u32x4* p = (const u32x4*)(eduf + (size_t)row * ND + k0 + ch * 8);
            u32x4 x = p[0], y = p[1];
            u32x4 o = { rne2(x.x, x.y), rne2(x.z, x.w), rne2(y.x, y.y), rne2(y.z, y.w) };
            *(u32x4*)&edu_s[row * 64 + ((ch ^ (row & 7)) * 8)] = o;
        }
        #pragma unroll
        for (int i = 0; i < 2; i++) {           // Wk: 2 chunks/thread
            const int g = tid * 2 + i, row = g >> 3, ch = g & 7;
            const u32x4* p = (const u32x4*)(wkf + (size_t)row * ND + k0 + ch * 8);
            u32x4 x = p[0], y = p[1];
            u32x4 o = { rne2(x.x, x.y), rne2(x.z, x.w), rne2(y.x, y.y), rne2(y.z, y.w) };
            *(u32x4*)&wk_s[row * 64 + ((ch ^ (row & 7)) * 8)] = o;
        }
        {                                        // Wv: 1 chunk/thread (32 rows)
            const int g = tid, row = g >> 3, ch = g & 7;
            const u32x4* p = (const u32x4*)(wvf + (size_t)row * ND + k0 + ch * 8);
            u32x4 x = p[0], y = p[1];
            u32x4 o = { rne2(x.x, x.y), rne2(x.z, x.w), rne2(y.x, y.y), rne2(y.z, y.w) };
            *(u32x4*)&wv_s[row * 64 + ((ch ^ (row & 7)) * 8)] = o;
        }
        __syncthreads();
        #pragma unroll
        for (int k32 = 0; k32 < 2; k32++) {
            const int cx = (((k32 * 4 + lg) ^ (lr & 7)) * 8);
            short8 eb = *(const short8*)&edu_s[(wvx * 16 + lr) * 64 + cx];
            #pragma unroll
            for (int jb = 0; jb < 4; jb++) {
                short8 ak = *(const short8*)&wk_s[(jb * 16 + lr) * 64 + cx];
                acc_k[jb] = __builtin_amdgcn_mfma_f32_16x16x32_bf16(ak, eb, acc_k[jb], 0, 0, 0);
            }
            #pragma unroll
            for (int jb = 0; jb < 2; jb++) {
                short8 av = *(const short8*)&wv_s[(jb * 16 + lr) * 64 + cx];
                acc_v[jb] = __builtin_amdgcn_mfma_f32_16x16x32_bf16(av, eb, acc_v[jb], 0, 0, 0);
            }
        }
    }

    __syncthreads();   // staging dead; region re-purposed as k_s / v_s
    {   // fragments -> k_s[t][d], v_s[t][e]  (lane holds col t = wvx*16+lr)
        const int t = wvx * 16 + lr;
        #pragma unroll
        for (int jb = 0; jb < 4; jb++) *(f32x4*)&k_s[t][jb * 16 + lg * 4] = acc_k[jb];
        #pragma unroll
        for (int jb = 0; jb < 2; jb++) *(f32x4*)&v_s[t][jb * 16 + lg * 4] = acc_v[jb];
    }
    __syncthreads();

    // ---- scan with REGISTER buckets: wave wvx owns speakers wvx, wvx+4.
    // lane owns (e = lane&31, d-half dh = lane>>5 -> 32 d's, 32 regs).
    const int e  = lane & 31;
    const int dh = lane >> 5;
    #pragma unroll
    for (int sp = 0; sp < 2; sp++) {
        const int s = wvx + sp * 4;
        float bk[32];
        #pragma unroll
        for (int j = 0; j < 32; j++) bk[j] = 0.f;
        for (int t = 0; t < NT; t++) {
            if (spk_s[t] != s) continue;    // wave-uniform
            const float vv = v_s[t][e];
            unsigned short* mpp = Mt +
                (((size_t)(b * NT + t) * NH + h) * HD + eh * 32 + e) * HD + dh * 32;
            #pragma unroll
            for (int q = 0; q < 4; q++) {
                #pragma unroll
                for (int j = 0; j < 8; j++)
                    bk[q * 8 + j] += k_s[t][dh * 32 + q * 8 + j] * vv;
                u32x4 o = { rne2(fbits(bk[q * 8 + 0]), fbits(bk[q * 8 + 1])),
                            rne2(fbits(bk[q * 8 + 2]), fbits(bk[q * 8 + 3])),
                            rne2(fbits(bk[q * 8 + 4]), fbits(bk[q * 8 + 5])),
                            rne2(fbits(bk[q * 8 + 6]), fbits(bk[q * 8 + 7])) };
                *(u32x4*)(mpp + q * 8) = o;
            }
        }
    }
}

// ---------------------------------------------------------------------------
// Kernel 2: fused bf16 MFMA  q^T = Wq_hp @ te^T (K=768), a = q @ M, residual.
// (round-13 exact — proven; round-17's Wq-to-regs reverted: scattered 16B
// fragment loads at 1536B row stride swamped the memory pipe)
// ---------------------------------------------------------------------------
__global__ __launch_bounds__(256, 2) void fused_qm(
    const unsigned short* __restrict__ te_b,
    const unsigned short* __restrict__ wq_b,
    const unsigned short* __restrict__ Mt,
    float* __restrict__ out)
{
    const int orig = blockIdx.x;
    const int id   = (orig & 7) * 192 + (orig >> 3);   // bijective XCD swizzle
    const int hp   = id % 6;
    const int bt   = id / 6;

    __shared__ __align__(16) unsigned short smem[32768];   // 65536 B
    unsigned short* te0 = smem;              // [128][64] swizzled chunks
    unsigned short* te1 = smem + 8192;
    unsigned short* wq0 = smem + 16384;
    unsigned short* wq1 = smem + 24576;
    unsigned short* q_s = smem;              // phase 2: [128][136]

    const int tid  = threadIdx.x;
    const int lane = tid & 63;
    const int wvx  = tid >> 6;
    const int lr   = lane & 15;
    const int lg   = lane >> 4;
    const int wm   = wvx >> 1;
    const int wn   = wvx & 1;
    const int r8   = lane >> 3;
    const int l8   = lane & 7;
    const int sswz = (l8 ^ r8) * 8;          // pre-swizzled source chunk (ush)

    const unsigned short* teb = te_b + (size_t)bt * NL * ND;
    const unsigned short* wqb = wq_b + (size_t)hp * 128 * ND;

    f32x4 acc[4][4];
    #pragma unroll
    for (int i = 0; i < 4; i++)
        #pragma unroll
        for (int j = 0; j < 4; j++) acc[i][j] = (f32x4){0.f, 0.f, 0.f, 0.f};

    auto STAGE = [&](unsigned short* tebuf, unsigned short* wqbuf, int k0) {
        #pragma unroll
        for (int j = 0; j < 4; j++) {
            const int rbase = wvx * 32 + j * 8;     // wave-uniform dest base
            gl2lds16(teb + (size_t)(rbase + r8) * ND + k0 + sswz, tebuf + rbase * 64);
            gl2lds16(wqb + (size_t)(rbase + r8) * ND + k0 + sswz, wqbuf + rbase * 64);
        }
    };
    auto COMPUTE = [&](const unsigned short* tes, const unsigned short* wqs) {
        #pragma unroll
        for (int k32 = 0; k32 < 2; k32++) {
            const int cx = (((k32 * 4 + lg) ^ (lr & 7)) * 8);
            short8 af[4], bfv[4];
            #pragma unroll
            for (int tm = 0; tm < 4; tm++)
                af[tm] = *(const short8*)&wqs[(wm * 64 + tm * 16 + lr) * 64 + cx];
            #pragma unroll
            for (int tn = 0; tn < 4; tn++)
                bfv[tn] = *(const short8*)&tes[(wn * 64 + tn * 16 + lr) * 64 + cx];
            #pragma unroll
            for (int tm = 0; tm < 4; tm++)
                #pragma unroll
                for (int tn = 0; tn < 4; tn++)
                    acc[tm][tn] = __builtin_amdgcn_mfma_f32_16x16x32_bf16(
                        af[tm], bfv[tn], acc[tm][tn], 0, 0, 0);
        }
    };

    // ---- prologue: tile 0 into buf0, full drain once ----
    STAGE(te0, wq0, 0);
    asm volatile("s_waitcnt vmcnt(0)" ::: "memory");
    __builtin_amdgcn_sched_barrier(0);
    __builtin_amdgcn_s_barrier();

    // ---- K-loop: 12 tiles, 2 per iteration, counted vmcnt (never 0 mid-loop)
    #pragma unroll
    for (int kt = 0; kt < 12; kt += 2) {
        STAGE(te1, wq1, (kt + 1) * 64);
        asm volatile("s_waitcnt vmcnt(8)" ::: "memory");   // tile kt complete
        __builtin_amdgcn_sched_barrier(0);
        __builtin_amdgcn_s_barrier();
        COMPUTE(te0, wq0);
        asm volatile("s_waitcnt lgkmcnt(0)" ::: "memory"); // reads retired
        __builtin_amdgcn_s_barrier();                      // buf0 free for reuse
        if (kt + 2 < 12) {
            STAGE(te0, wq0, (kt + 2) * 64);
            asm volatile("s_waitcnt vmcnt(8)" ::: "memory");
        } else {
            asm volatile("s_waitcnt vmcnt(0)" ::: "memory");
        }
        __builtin_amdgcn_sched_barrier(0);
        __builtin_amdgcn_s_barrier();
        COMPUTE(te1, wq1);
        asm volatile("s_waitcnt lgkmcnt(0)" ::: "memory");
        __builtin_amdgcn_s_barrier();                      // buf1 free for reuse
    }

    // ---- q^T C-frags -> row-major bf16 q_s[l][d] (8B packed writes) ----
    #pragma unroll
    for (int tm = 0; tm < 4; tm++) {
        const int d0 = wm * 64 + tm * 16 + lg * 4;
        #pragma unroll
        for (int tn = 0; tn < 4; tn++) {
            const int ltok = wn * 64 + tn * 16 + lr;
            f32x4 a = acc[tm][tn];
            uint2 w2;
            w2.x = (unsigned)f2b(a.x) | ((unsigned)f2b(a.y) << 16);
            w2.y = (unsigned)f2b(a.z) | ((unsigned)f2b(a.w) << 16);
            *(uint2*)&q_s[ltok * 136 + d0] = w2;
        }
    }

    // ---- GEMM2 B-frags straight from global Mt (L2-hot); issue pre-barrier --
    const int h2 = wvx & 1;
    const int lh = wvx >> 1;
    const unsigned short* mp = Mt + ((size_t)(bt * NH) + hp * 2 + h2) * (HD * HD);
    short8 bfr[8];
    #pragma unroll
    for (int tn = 0; tn < 4; tn++)
        #pragma unroll
        for (int k32 = 0; k32 < 2; k32++)
            bfr[tn * 2 + k32] =
                *(const short8*)&mp[(tn * 16 + lr) * 64 + k32 * 32 + lg * 8];
    __syncthreads();            // q_s visible

    // ---- GEMM2: per-wave one (token-half, head), 64x64, K=64 ----
    f32x4 acc2[4][4];
    #pragma unroll
    for (int i = 0; i < 4; i++)
        #pragma unroll
        for (int j = 0; j < 4; j++) acc2[i][j] = (f32x4){0.f, 0.f, 0.f, 0.f};

    #pragma unroll
    for (int k32 = 0; k32 < 2; k32++) {
        const int ko = k32 * 32 + lg * 8;
        short8 af[4];
        #pragma unroll
        for (int tm = 0; tm < 4; tm++)
            af[tm] = *(const short8*)&q_s[(lh * 64 + tm * 16 + lr) * 136 + h2 * 64 + ko];
        #pragma unroll
        for (int tm = 0; tm < 4; tm++)
            #pragma unroll
            for (int tn = 0; tn < 4; tn++)
                acc2[tm][tn] = __builtin_amdgcn_mfma_f32_16x16x32_bf16(
                    af[tm], bfr[tn * 2 + k32], acc2[tm][tn], 0, 0, 0);
    }

    // ---- epilogue: out = bf16(te) + a (te_b L2-hot from staging) ----
    float* ob = out + (size_t)bt * NL * ND;
    #pragma unroll
    for (int tm = 0; tm < 4; tm++) {
        const int l0 = lh * 64 + tm * 16 + lg * 4;
        #pragma unroll
        for (int tn = 0; tn < 4; tn++) {
            const int cg = hp * 128 + h2 * 64 + tn * 16 + lr;
            f32x4 a = acc2[tm][tn];
            #pragma unroll
            for (int r = 0; r < 4; r++) {
                size_t gi = (size_t)(l0 + r) * ND + cg;
                ob[gi] = b2f(teb[gi]) + a[r];
            }
        }
    }
}

// ---------------------------------------------------------------------------
extern "C" void kernel_launch(void* const* d_in, const int* in_sizes, int n_in,
                              void* d_out, int out_size, void* d_ws, size_t ws_size,
                              hipStream_t stream)
{
    const int*   spk = (const int*)d_in[1];
    const float* te  = (const float*)d_in[2];
    const float* edu = (const float*)d_in[3];
    const float* Wk  = (const float*)d_in[4];
    const float* Wv  = (const float*)d_in[5];
    const float* Wq  = (const float*)d_in[6];
    float* out = (float*)d_out;

    // ws layout (ush units), ~76.7 MB total:
    unsigned short* bf    = (unsigned short*)d_ws;
    unsigned short* te_bb = bf;                          // 25165824
    unsigned short* wq_bb = bf + 25165824u;              //   589824
    unsigned short* Mtbuf = bf + 25755648u;              // 12582912

    prep_all<<<3240, 256, 0, stream>>>(te, Wq, edu, Wk, Wv, spk,
                                       te_bb, wq_bb, Mtbuf);
    fused_qm<<<6 * NT * NB, 256, 0, stream>>>(te_bb, wq_bb, Mtbuf, out);
}

// Round 19
// 96.294 us; speedup vs baseline: 1.4763x; 1.0809x over previous
//
#include <hip/hip_runtime.h>
#include <hip/hip_bf16.h>

// Shapes (fixed): B=4, T=64, L=128, D=768, H=12, d=64
#define NB 4
#define NT 64
#define NL 128
#define ND 768
#define NH 12
#define HD 64

typedef __attribute__((ext_vector_type(8))) short short8;
typedef __attribute__((ext_vector_type(4))) float f32x4;
typedef __attribute__((ext_vector_type(4))) unsigned int u32x4;

typedef __attribute__((address_space(3))) unsigned int lds_u32;
typedef __attribute__((address_space(1))) const unsigned int glob_u32;

static __device__ __forceinline__ unsigned short f2b(float x) {
    __hip_bfloat16 h = __float2bfloat16(x);   // RNE
    return *reinterpret_cast<unsigned short*>(&h);
}
static __device__ __forceinline__ float b2f(unsigned short u) {
    unsigned int v = ((unsigned int)u) << 16;
    union { unsigned int i; float f; } c; c.i = v; return c.f;
}
static __device__ __forceinline__ unsigned fbits(float f) {
    union { float f; unsigned u; } c; c.f = f; return c.u;
}
// async global->LDS, 16B/lane; LDS dest = base + lane*16 (wave-uniform base)
static __device__ __forceinline__ void gl2lds16(const void* g, void* l) {
    __builtin_amdgcn_global_load_lds((glob_u32*)g, (lds_u32*)l, 16, 0, 0);
}
// branchless RNE fp32->bf16 for two elems, packed into one u32 (no NaN inputs)
static __device__ __forceinline__ unsigned rne2(unsigned lo, unsigned hi) {
    lo += 0x7FFFu + ((lo >> 16) & 1u);
    hi += 0x7FFFu + ((hi >> 16) & 1u);
    return __builtin_amdgcn_perm(hi, lo, 0x07060302u);  // [hi31:16 | lo31:16]
}

// ---------------------------------------------------------------------------
// Kernel 1 (prep_all): merged, LDS = 52.5 KB -> 3 blocks/CU for converts.
//  blocks [0,192):     kvm QUADRANT-split (e-half x d-half): K/V proj (bf16
//                      MFMA, self-converting staging) + LDS-bucket scan -> Mt.
//                      bucket [8][32][33] fits because each block owns a
//                      32e x 32d quadrant. No register-bucket -> no spill.
//  blocks [192,3264):  dense te fp32->bf16 convert (16B/lane, ILP-8, NT)
//  blocks [3264,3336): Wq fp32->bf16 convert
// ---------------------------------------------------------------------------
__global__ __launch_bounds__(256) void prep_all(
    const float* __restrict__ te, const float* __restrict__ Wq,
    const float* __restrict__ edu, const float* __restrict__ Wk,
    const float* __restrict__ Wv, const int* __restrict__ spk,
    unsigned short* __restrict__ te_b, unsigned short* __restrict__ wq_b,
    unsigned short* __restrict__ Mt)
{
    // LDS layout (52480 B total):
    //  bucket f32[8][32][33] @0      (33792 B)   [scan phase]
    //  k_s    f32[64][36]    @33792  ( 9216 B)
    //  v_s    f32[64][36]    @43008  ( 9216 B)
    //  spk_s  int[64]        @52224  (  256 B)
    //  staging overlay @0..16384: edu_s 8192 | wk_s 4096 | wv_s 4096
    __shared__ __align__(16) unsigned char sm[52480];
    const int tid = threadIdx.x;
    const unsigned bid = blockIdx.x;

    if (bid >= 192u) {
        if (bid < 3264u) {
            // ---- te convert: 6291456 4-float chunks = 3072 * 2048 ----
            const unsigned base = (bid - 192u) * 2048u + tid;
            u32x4 a[8];
            #pragma unroll
            for (int i = 0; i < 8; i++)
                a[i] = __builtin_nontemporal_load((const u32x4*)te + base + i * 256u);
            #pragma unroll
            for (int i = 0; i < 8; i++) {
                uint2 o;
                o.x = rne2(a[i].x, a[i].y);
                o.y = rne2(a[i].z, a[i].w);
                *(uint2*)(te_b + (size_t)(base + i * 256u) * 4u) = o;
            }
        } else {
            // ---- Wq convert: 147456 chunks = 72 * 2048 ----
            const unsigned base = (bid - 3264u) * 2048u + tid;
            u32x4 a[8];
            #pragma unroll
            for (int i = 0; i < 8; i++)
                a[i] = *((const u32x4*)Wq + base + i * 256u);
            #pragma unroll
            for (int i = 0; i < 8; i++) {
                uint2 o;
                o.x = rne2(a[i].x, a[i].y);
                o.y = rne2(a[i].z, a[i].w);
                *(uint2*)(wq_b + (size_t)(base + i * 256u) * 4u) = o;
            }
        }
        return;
    }

    // ---- kvm path: bid < 192 -> (quadrant, h, b) ----
    const int q   = bid / 48;        // 0..3
    const int rem = bid % 48;
    const int h   = rem % 12;
    const int b   = rem / 12;
    const int eh  = q >> 1;          // e-half
    const int dhh = q & 1;           // d-half

    float (*bucket)[32][33] = (float (*)[32][33])(sm);       // [spk][e][dloc]
    float (*k_s)[36]        = (float (*)[36])(sm + 33792);   // [t][dloc 0..31]
    float (*v_s)[36]        = (float (*)[36])(sm + 43008);   // [t][eloc 0..31]
    int* spk_s              = (int*)(sm + 52224);
    unsigned short* edu_s   = (unsigned short*)(sm);         // staging overlay
    unsigned short* wk_s    = (unsigned short*)(sm + 8192);
    unsigned short* wv_s    = (unsigned short*)(sm + 12288);

    const int lane = tid & 63, wvx = tid >> 6;
    const int lr = lane & 15, lg = lane >> 4;

    if (tid < 64) spk_s[tid] = spk[b * NT + tid];

    const float* eduf = edu + (size_t)(b * 64) * ND;
    const float* wkf  = Wk  + (size_t)(h * 64 + dhh * 32) * ND;
    const float* wvf  = Wv  + (size_t)(h * 64 + eh * 32) * ND;

    f32x4 acc_k[2], acc_v[2];
    #pragma unroll
    for (int i = 0; i < 2; i++) acc_k[i] = (f32x4){0.f, 0.f, 0.f, 0.f};
    #pragma unroll
    for (int i = 0; i < 2; i++) acc_v[i] = (f32x4){0.f, 0.f, 0.f, 0.f};

    for (int k0 = 0; k0 < ND; k0 += 64) {
        __syncthreads();
        // self-convert staging: fp32 load -> rne2 -> swizzled bf16 ds_write
        #pragma unroll
        for (int i = 0; i < 2; i++) {           // edu: 2 chunks/thread, 64 rows
            const int g = tid * 2 + i, row = g >> 3, ch = g & 7;
            const u32x4* p = (const u32x4*)(eduf + (size_t)row * ND + k0 + ch * 8);
            u32x4 x = p[0], y = p[1];
            u32x4 o = { rne2(x.x, x.y), rne2(x.z, x.w), rne2(y.x, y.y), rne2(y.z, y.w) };
            *(u32x4*)&edu_s[row * 64 + ((ch ^ (row & 7)) * 8)] = o;
        }
        {                                        // Wk: 1 chunk/thread, 32 rows
            const int g = tid, row = g >> 3, ch = g & 7;
            const u32x4* p = (const u32x4*)(wkf + (size_t)row * ND + k0 + ch * 8);
            u32x4 x = p[0], y = p[1];
            u32x4 o = { rne2(x.x, x.y), rne2(x.z, x.w), rne2(y.x, y.y), rne2(y.z, y.w) };
            *(u32x4*)&wk_s[row * 64 + ((ch ^ (row & 7)) * 8)] = o;
        }
        {                                        // Wv: 1 chunk/thread, 32 rows
            const int g = tid, row = g >> 3, ch = g & 7;
            const u32x4* p = (const u32x4*)(wvf + (size_t)row * ND + k0 + ch * 8);
            u32x4 x = p[0], y = p[1];
            u32x4 o = { rne2(x.x, x.y), rne2(x.z, x.w), rne2(y.x, y.y), rne2(y.z, y.w) };
            *(u32x4*)&wv_s[row * 64 + ((ch ^ (row & 7)) * 8)] = o;
        }
        __syncthreads();
        #pragma unroll
        for (int k32 = 0; k32 < 2; k32++) {
            const int cx = (((k32 * 4 + lg) ^ (lr & 7)) * 8);
            short8 eb = *(const short8*)&edu_s[(wvx * 16 + lr) * 64 + cx];
            #pragma unroll
            for (int jb = 0; jb < 2; jb++) {
                short8 ak = *(const short8*)&wk_s[(jb * 16 + lr) * 64 + cx];
                acc_k[jb] = __builtin_amdgcn_mfma_f32_16x16x32_bf16(ak, eb, acc_k[jb], 0, 0, 0);
            }
            #pragma unroll
            for (int jb = 0; jb < 2; jb++) {
                short8 av = *(const short8*)&wv_s[(jb * 16 + lr) * 64 + cx];
                acc_v[jb] = __builtin_amdgcn_mfma_f32_16x16x32_bf16(av, eb, acc_v[jb], 0, 0, 0);
            }
        }
    }

    __syncthreads();   // all staging reads done; overlay region -> bucket
    // zero bucket (33792 B) + write fragments (k_s/v_s are non-overlapping)
    { float* p = &bucket[0][0][0];
      for (int i = tid; i < 8 * 32 * 33; i += 256) p[i] = 0.f; }
    {   // lane holds col t = wvx*16+lr, rows jb*16 + lg*4 + r (local d / e)
        const int t = wvx * 16 + lr;
        #pragma unroll
        for (int jb = 0; jb < 2; jb++) *(f32x4*)&k_s[t][jb * 16 + lg * 4] = acc_k[jb];
        #pragma unroll
        for (int jb = 0; jb < 2; jb++) *(f32x4*)&v_s[t][jb * 16 + lg * 4] = acc_v[jb];
    }
    __syncthreads();

    // ---- bucket scan: thread owns (eloc = tid&31, 4 d's at dg*4) ----
    const int e = tid & 31, dg = tid >> 5;
    for (int t = 0; t < NT; t++) {
        const int s = spk_s[t];
        const float vv = v_s[t][e];
        float m0 = bucket[s][e][dg * 4 + 0] + k_s[t][dg * 4 + 0] * vv;
        float m1 = bucket[s][e][dg * 4 + 1] + k_s[t][dg * 4 + 1] * vv;
        float m2 = bucket[s][e][dg * 4 + 2] + k_s[t][dg * 4 + 2] * vv;
        float m3 = bucket[s][e][dg * 4 + 3] + k_s[t][dg * 4 + 3] * vv;
        bucket[s][e][dg * 4 + 0] = m0;
        bucket[s][e][dg * 4 + 1] = m1;
        bucket[s][e][dg * 4 + 2] = m2;
        bucket[s][e][dg * 4 + 3] = m3;
        uint2 o;
        o.x = rne2(fbits(m0), fbits(m1));
        o.y = rne2(fbits(m2), fbits(m3));
        unsigned short* mpp = Mt +
            (((size_t)(b * NT + t) * NH + h) * HD + eh * 32 + e) * HD + dhh * 32 + dg * 4;
        *(uint2*)mpp = o;
    }
}

// ---------------------------------------------------------------------------
// Kernel 2: fused bf16 MFMA  q^T = Wq_hp @ te^T (K=768), a = q @ M, residual.
// (round-13 exact — proven)
// ---------------------------------------------------------------------------
__global__ __launch_bounds__(256, 2) void fused_qm(
    const unsigned short* __restrict__ te_b,
    const unsigned short* __restrict__ wq_b,
    const unsigned short* __restrict__ Mt,
    float* __restrict__ out)
{
    const int orig = blockIdx.x;
    const int id   = (orig & 7) * 192 + (orig >> 3);   // bijective XCD swizzle
    const int hp   = id % 6;
    const int bt   = id / 6;

    __shared__ __align__(16) unsigned short smem[32768];   // 65536 B
    unsigned short* te0 = smem;              // [128][64] swizzled chunks
    unsigned short* te1 = smem + 8192;
    unsigned short* wq0 = smem + 16384;
    unsigned short* wq1 = smem + 24576;
    unsigned short* q_s = smem;              // phase 2: [128][136]

    const int tid  = threadIdx.x;
    const int lane = tid & 63;
    const int wvx  = tid >> 6;
    const int lr   = lane & 15;
    const int lg   = lane >> 4;
    const int wm   = wvx >> 1;
    const int wn   = wvx & 1;
    const int r8   = lane >> 3;
    const int l8   = lane & 7;
    const int sswz = (l8 ^ r8) * 8;          // pre-swizzled source chunk (ush)

    const unsigned short* teb = te_b + (size_t)bt * NL * ND;
    const unsigned short* wqb = wq_b + (size_t)hp * 128 * ND;

    f32x4 acc[4][4];
    #pragma unroll
    for (int i = 0; i < 4; i++)
        #pragma unroll
        for (int j = 0; j < 4; j++) acc[i][j] = (f32x4){0.f, 0.f, 0.f, 0.f};

    auto STAGE = [&](unsigned short* tebuf, unsigned short* wqbuf, int k0) {
        #pragma unroll
        for (int j = 0; j < 4; j++) {
            const int rbase = wvx * 32 + j * 8;     // wave-uniform dest base
            gl2lds16(teb + (size_t)(rbase + r8) * ND + k0 + sswz, tebuf + rbase * 64);
            gl2lds16(wqb + (size_t)(rbase + r8) * ND + k0 + sswz, wqbuf + rbase * 64);
        }
    };
    auto COMPUTE = [&](const unsigned short* tes, const unsigned short* wqs) {
        #pragma unroll
        for (int k32 = 0; k32 < 2; k32++) {
            const int cx = (((k32 * 4 + lg) ^ (lr & 7)) * 8);
            short8 af[4], bfv[4];
            #pragma unroll
            for (int tm = 0; tm < 4; tm++)
                af[tm] = *(const short8*)&wqs[(wm * 64 + tm * 16 + lr) * 64 + cx];
            #pragma unroll
            for (int tn = 0; tn < 4; tn++)
                bfv[tn] = *(const short8*)&tes[(wn * 64 + tn * 16 + lr) * 64 + cx];
            #pragma unroll
            for (int tm = 0; tm < 4; tm++)
                #pragma unroll
                for (int tn = 0; tn < 4; tn++)
                    acc[tm][tn] = __builtin_amdgcn_mfma_f32_16x16x32_bf16(
                        af[tm], bfv[tn], acc[tm][tn], 0, 0, 0);
        }
    };

    // ---- prologue: tile 0 into buf0, full drain once ----
    STAGE(te0, wq0, 0);
    asm volatile("s_waitcnt vmcnt(0)" ::: "memory");
    __builtin_amdgcn_sched_barrier(0);
    __builtin_amdgcn_s_barrier();

    // ---- K-loop: 12 tiles, 2 per iteration, counted vmcnt (never 0 mid-loop)
    #pragma unroll
    for (int kt = 0; kt < 12; kt += 2) {
        STAGE(te1, wq1, (kt + 1) * 64);
        asm volatile("s_waitcnt vmcnt(8)" ::: "memory");   // tile kt complete
        __builtin_amdgcn_sched_barrier(0);
        __builtin_amdgcn_s_barrier();
        COMPUTE(te0, wq0);
        asm volatile("s_waitcnt lgkmcnt(0)" ::: "memory"); // reads retired
        __builtin_amdgcn_s_barrier();                      // buf0 free for reuse
        if (kt + 2 < 12) {
            STAGE(te0, wq0, (kt + 2) * 64);
            asm volatile("s_waitcnt vmcnt(8)" ::: "memory");
        } else {
            asm volatile("s_waitcnt vmcnt(0)" ::: "memory");
        }
        __builtin_amdgcn_sched_barrier(0);
        __builtin_amdgcn_s_barrier();
        COMPUTE(te1, wq1);
        asm volatile("s_waitcnt lgkmcnt(0)" ::: "memory");
        __builtin_amdgcn_s_barrier();                      // buf1 free for reuse
    }

    // ---- q^T C-frags -> row-major bf16 q_s[l][d] (8B packed writes) ----
    #pragma unroll
    for (int tm = 0; tm < 4; tm++) {
        const int d0 = wm * 64 + tm * 16 + lg * 4;
        #pragma unroll
        for (int tn = 0; tn < 4; tn++) {
            const int ltok = wn * 64 + tn * 16 + lr;
            f32x4 a = acc[tm][tn];
            uint2 w2;
            w2.x = (unsigned)f2b(a.x) | ((unsigned)f2b(a.y) << 16);
            w2.y = (unsigned)f2b(a.z) | ((unsigned)f2b(a.w) << 16);
            *(uint2*)&q_s[ltok * 136 + d0] = w2;
        }
    }

    // ---- GEMM2 B-frags straight from global Mt (L2-hot); issue pre-barrier --
    const int h2 = wvx & 1;
    const int lh = wvx >> 1;
    const unsigned short* mp = Mt + ((size_t)(bt * NH) + hp * 2 + h2) * (HD * HD);
    short8 bfr[8];
    #pragma unroll
    for (int tn = 0; tn < 4; tn++)
        #pragma unroll
        for (int k32 = 0; k32 < 2; k32++)
            bfr[tn * 2 + k32] =
                *(const short8*)&mp[(tn * 16 + lr) * 64 + k32 * 32 + lg * 8];
    __syncthreads();            // q_s visible

    // ---- GEMM2: per-wave one (token-half, head), 64x64, K=64 ----
    f32x4 acc2[4][4];
    #pragma unroll
    for (int i = 0; i < 4; i++)
        #pragma unroll
        for (int j = 0; j < 4; j++) acc2[i][j] = (f32x4){0.f, 0.f, 0.f, 0.f};

    #pragma unroll
    for (int k32 = 0; k32 < 2; k32++) {
        const int ko = k32 * 32 + lg * 8;
        short8 af[4];
        #pragma unroll
        for (int tm = 0; tm < 4; tm++)
            af[tm] = *(const short8*)&q_s[(lh * 64 + tm * 16 + lr) * 136 + h2 * 64 + ko];
        #pragma unroll
        for (int tm = 0; tm < 4; tm++)
            #pragma unroll
            for (int tn = 0; tn < 4; tn++)
                acc2[tm][tn] = __builtin_amdgcn_mfma_f32_16x16x32_bf16(
                    af[tm], bfr[tn * 2 + k32], acc2[tm][tn], 0, 0, 0);
    }

    // ---- epilogue: out = bf16(te) + a (te_b L2-hot from staging) ----
    float* ob = out + (size_t)bt * NL * ND;
    #pragma unroll
    for (int tm = 0; tm < 4; tm++) {
        const int l0 = lh * 64 + tm * 16 + lg * 4;
        #pragma unroll
        for (int tn = 0; tn < 4; tn++) {
            const int cg = hp * 128 + h2 * 64 + tn * 16 + lr;
            f32x4 a = acc2[tm][tn];
            #pragma unroll
            for (int r = 0; r < 4; r++) {
                size_t gi = (size_t)(l0 + r) * ND + cg;
                ob[gi] = b2f(teb[gi]) + a[r];
            }
        }
    }
}

// ---------------------------------------------------------------------------
extern "C" void kernel_launch(void* const* d_in, const int* in_sizes, int n_in,
                              void* d_out, int out_size, void* d_ws, size_t ws_size,
                              hipStream_t stream)
{
    const int*   spk = (const int*)d_in[1];
    const float* te  = (const float*)d_in[2];
    const float* edu = (const float*)d_in[3];
    const float* Wk  = (const float*)d_in[4];
    const float* Wv  = (const float*)d_in[5];
    const float* Wq  = (const float*)d_in[6];
    float* out = (float*)d_out;

    // ws layout (ush units), ~76.7 MB total:
    unsigned short* bf    = (unsigned short*)d_ws;
    unsigned short* te_bb = bf;                          // 25165824
    unsigned short* wq_bb = bf + 25165824u;              //   589824
    unsigned short* Mtbuf = bf + 25755648u;              // 12582912

    prep_all<<<3336, 256, 0, stream>>>(te, Wq, edu, Wk, Wv, spk,
                                       te_bb, wq_bb, Mtbuf);
    fused_qm<<<6 * NT * NB, 256, 0, stream>>>(te_bb, wq_bb, Mtbuf, out);
}